// Round 1
// baseline (598.972 us; speedup 1.0000x reference)
//
#include <hip/hip_runtime.h>
#include <hip/hip_bf16.h>

// MLPPredictor: score[e][c] = dot(concat(h[src[e]], h[dst[e]], edge_h[e]), W[c]) + b[c]
// E=600000, D=128, EDIM=128, C=10.
// Decomposition: 1 thread = 1 edge, all 10 classes in registers (no cross-lane
// reduction). K-tiled LDS staging (256 edges x 32 feats) for coalesced gathers.
// XOR-swizzled float4 LDS layout -> conflict-free b128 reads/writes.
// Weights read via block-uniform indices -> scalar loads (s_load), no LDS traffic.

#define E_PER_BLOCK 256
#define KT 32            // features per tile
#define NTILE 12         // 384 / 32
#define NC 10

__global__ __launch_bounds__(256, 4) void mlp_edge_kernel(
    const float* __restrict__ h,      // [N,128]
    const float* __restrict__ eh,     // [E,128]
    const float* __restrict__ Ww,     // [10,384]
    const float* __restrict__ Wb,     // [10]
    const int*   __restrict__ src,    // [E]
    const int*   __restrict__ dst,    // [E]
    float* __restrict__ out,          // [E,10]
    int E)
{
    __shared__ float tile[E_PER_BLOCK][KT];   // 32 KB, xor-swizzled float4 chunks
    __shared__ int s_sh[E_PER_BLOCK];
    __shared__ int d_sh[E_PER_BLOCK];

    const int tid = threadIdx.x;
    const long blockStart = (long)blockIdx.x * E_PER_BLOCK;
    const long myE = blockStart + tid;

    // stage src/dst indices for the whole block (guard tail with 0)
    {
        int s = 0, d = 0;
        if (myE < E) { s = src[myE]; d = dst[myE]; }
        s_sh[tid] = s;
        d_sh[tid] = d;
    }
    __syncthreads();

    // accumulators init = bias (uniform scalar loads)
    float acc[NC];
#pragma unroll
    for (int c = 0; c < NC; ++c) acc[c] = Wb[c];

    const int quad  = tid & 7;    // float4 slot within a 32-float row segment
    const int rbase = tid >> 3;   // 0..31

#pragma unroll 1
    for (int j = 0; j < NTILE; ++j) {
        const int kg = j * KT;    // global feature offset 0..352 (uniform)

        // ---- stage 256 edges x 32 features into LDS (coalesced 128B segments) ----
#pragma unroll
        for (int i = 0; i < 8; ++i) {
            const int row = i * 32 + rbase;
            const long er = blockStart + row;
            const float* gsrc;
            if (j < 4) {
                gsrc = h + (long)s_sh[row] * 128 + (kg + quad * 4);
            } else if (j < 8) {
                gsrc = h + (long)d_sh[row] * 128 + ((kg - 128) + quad * 4);
            } else {
                const long ec = (er < E) ? er : (long)(E - 1);
                gsrc = eh + ec * 128 + ((kg - 256) + quad * 4);
            }
            const float4 v = *(const float4*)gsrc;
            const int sq = quad ^ (row & 7);          // xor swizzle chunk
            *(float4*)&tile[row][sq * 4] = v;
        }
        __syncthreads();

        // ---- each thread consumes its own row: 8 x float4, FMA vs scalar weights ----
#pragma unroll
        for (int k4 = 0; k4 < 8; ++k4) {
            const int sq = k4 ^ (tid & 7);
            const float4 f = *(const float4*)&tile[tid][sq * 4];
#pragma unroll
            for (int c = 0; c < NC; ++c) {
                const float* w = Ww + c * 384 + kg + k4 * 4;  // uniform -> s_load
                acc[c] = fmaf(f.x, w[0], acc[c]);
                acc[c] = fmaf(f.y, w[1], acc[c]);
                acc[c] = fmaf(f.z, w[2], acc[c]);
                acc[c] = fmaf(f.w, w[3], acc[c]);
            }
        }
        __syncthreads();
    }

    // ---- store 10 outputs per edge; e*10 floats = 40B -> 8B aligned, use float2 ----
    if (myE < E) {
        float* o = out + myE * NC;
#pragma unroll
        for (int c = 0; c < NC; c += 2) {
            float2 v;
            v.x = acc[c];
            v.y = acc[c + 1];
            *(float2*)(o + c) = v;
        }
    }
}

extern "C" void kernel_launch(void* const* d_in, const int* in_sizes, int n_in,
                              void* d_out, int out_size, void* d_ws, size_t ws_size,
                              hipStream_t stream) {
    const float* h   = (const float*)d_in[0];
    const float* eh  = (const float*)d_in[1];
    const float* Ww  = (const float*)d_in[2];
    const float* Wb  = (const float*)d_in[3];
    const int*   src = (const int*)d_in[4];
    const int*   dst = (const int*)d_in[5];
    float* out = (float*)d_out;

    const int E = in_sizes[4];
    const int blocks = (E + E_PER_BLOCK - 1) / E_PER_BLOCK;
    mlp_edge_kernel<<<blocks, E_PER_BLOCK, 0, stream>>>(h, eh, Ww, Wb, src, dst, out, E);
}